// Round 1
// baseline (1587.520 us; speedup 1.0000x reference)
//
#include <hip/hip_runtime.h>

#define D 128
#define TILE 32

// ---------------------------------------------------------------------------
// Typed linear: Y[n,:] = X[n,:] @ W[ntype[n],:,:]   (X: [n,128], W: [2,128,128])
// Block: 256 threads, 32 nodes. Each thread: 4 nodes x 4 outs.
// ntype is sorted, so almost all blocks are type-uniform -> fast path.
// Safe to run in-place (Y == X): each block reads only its own 32 rows into
// LDS before any global write.
// ---------------------------------------------------------------------------
__global__ __launch_bounds__(256) void typed_linear_kernel(
    const float* __restrict__ X, const float* __restrict__ W,
    const int* __restrict__ ntype, float* __restrict__ Y, int n)
{
    __shared__ float xs[TILE][D + 4];     // +4 pad: keeps float4 alignment, breaks bank stride
    __shared__ float ws[2][TILE][D];      // one k-chunk of W per type

    const int t  = threadIdx.x;
    const int bn = blockIdx.x * TILE;

    // stage x tile (coalesced float4 loads)
    #pragma unroll
    for (int i = 0; i < 4; ++i) {
        int idx  = t + i * 256;           // 0..1023 float4 slots
        int node = idx >> 5;              // 32 float4 per row
        int c4   = idx & 31;
        float4 v = make_float4(0.f, 0.f, 0.f, 0.f);
        if (bn + node < n)
            v = reinterpret_cast<const float4*>(X)[(size_t)(bn + node) * (D / 4) + c4];
        *reinterpret_cast<float4*>(&xs[node][c4 * 4]) = v;
    }

    const int g  = t >> 5;    // node group 0..7
    const int oq = t & 31;    // out-quad 0..31

    const int last = (bn + TILE - 1 < n) ? bn + TILE - 1 : n - 1;
    const int tmin = ntype[bn];
    const int tmax = ntype[last];
    const bool uni = (tmin == tmax);

    int ty[4];
    #pragma unroll
    for (int i = 0; i < 4; ++i) {
        int node = bn + g * 4 + i;
        ty[i] = (node < n) ? ntype[node] : tmin;
    }

    float acc[4][4] = {};

    for (int kb = 0; kb < D; kb += TILE) {
        __syncthreads();
        // stage W k-chunk(s): 32 x 128 floats per type
        if (uni) {
            #pragma unroll
            for (int i = 0; i < 4; ++i) {
                int idx = t + i * 256;            // 0..1023 float4
                int kk  = idx >> 5;
                int c4  = idx & 31;
                float4 w = reinterpret_cast<const float4*>(W)
                    [(size_t)tmin * (D * D / 4) + (size_t)(kb + kk) * (D / 4) + c4];
                *reinterpret_cast<float4*>(&ws[tmin][kk][c4 * 4]) = w;
            }
        } else {
            #pragma unroll
            for (int tt = 0; tt < 2; ++tt) {
                #pragma unroll
                for (int i = 0; i < 4; ++i) {
                    int idx = t + i * 256;
                    int kk  = idx >> 5;
                    int c4  = idx & 31;
                    float4 w = reinterpret_cast<const float4*>(W)
                        [(size_t)tt * (D * D / 4) + (size_t)(kb + kk) * (D / 4) + c4];
                    *reinterpret_cast<float4*>(&ws[tt][kk][c4 * 4]) = w;
                }
            }
        }
        __syncthreads();

        if (uni) {
            #pragma unroll
            for (int kk = 0; kk < TILE; ++kk) {
                float4 w = *reinterpret_cast<const float4*>(&ws[tmin][kk][oq * 4]);
                #pragma unroll
                for (int i = 0; i < 4; ++i) {
                    float xv = xs[g * 4 + i][kb + kk];
                    acc[i][0] += xv * w.x;
                    acc[i][1] += xv * w.y;
                    acc[i][2] += xv * w.z;
                    acc[i][3] += xv * w.w;
                }
            }
        } else {
            #pragma unroll
            for (int kk = 0; kk < TILE; ++kk) {
                #pragma unroll
                for (int i = 0; i < 4; ++i) {
                    float xv = xs[g * 4 + i][kb + kk];
                    float4 w = *reinterpret_cast<const float4*>(&ws[ty[i]][kk][oq * 4]);
                    acc[i][0] += xv * w.x;
                    acc[i][1] += xv * w.y;
                    acc[i][2] += xv * w.z;
                    acc[i][3] += xv * w.w;
                }
            }
        }
    }

    #pragma unroll
    for (int i = 0; i < 4; ++i) {
        int node = bn + g * 4 + i;
        if (node < n)
            reinterpret_cast<float4*>(Y)[(size_t)node * (D / 4) + oq] =
                make_float4(acc[i][0], acc[i][1], acc[i][2], acc[i][3]);
    }
}

// ---------------------------------------------------------------------------
// Edge scatter: H[dst[e],:] += V[src[e],:]  -- 32 lanes per edge, float4 each.
// unsafeAtomicAdd -> hardware global_atomic_add_f32 (no CAS loop).
// ---------------------------------------------------------------------------
__global__ __launch_bounds__(256) void scatter_kernel(
    const float* __restrict__ V, const int* __restrict__ src,
    const int* __restrict__ dst, float* __restrict__ H, int ne)
{
    long long tid = (long long)blockIdx.x * blockDim.x + threadIdx.x;
    int e    = (int)(tid >> 5);
    int lane = (int)(tid & 31);
    if (e >= ne) return;

    int s = src[e];
    int d = dst[e];
    float4 v = reinterpret_cast<const float4*>(V)[(size_t)s * (D / 4) + lane];
    float* hp = H + (size_t)d * D + lane * 4;
    unsafeAtomicAdd(hp + 0, v.x);
    unsafeAtomicAdd(hp + 1, v.y);
    unsafeAtomicAdd(hp + 2, v.z);
    unsafeAtomicAdd(hp + 3, v.w);
}

// ---------------------------------------------------------------------------
extern "C" void kernel_launch(void* const* d_in, const int* in_sizes, int n_in,
                              void* d_out, int out_size, void* d_ws, size_t ws_size,
                              hipStream_t stream)
{
    const float* x     = (const float*)d_in[0];
    const int*   ntype = (const int*)d_in[1];
    const int*   src   = (const int*)d_in[2];
    const int*   dst   = (const int*)d_in[3];
    const float* Wv    = (const float*)d_in[4];
    const float* Wa    = (const float*)d_in[5];

    const int n  = in_sizes[0] / D;   // 100000 nodes
    const int ne = in_sizes[2];       // 800000 edges

    float* v   = (float*)d_ws;        // [n,128] scratch
    float* out = (float*)d_out;       // used as h accumulator, then final out in-place

    // h accumulator must start at zero
    hipMemsetAsync(out, 0, (size_t)out_size * sizeof(float), stream);

    const int nblk = (n + TILE - 1) / TILE;
    typed_linear_kernel<<<nblk, 256, 0, stream>>>(x, Wv, ntype, v, n);

    const int sblk = (int)(((long long)ne * 32 + 255) / 256);
    scatter_kernel<<<sblk, 256, 0, stream>>>(v, src, dst, out, ne);

    // in-place: out = out @ W_a[ntype]
    typed_linear_kernel<<<nblk, 256, 0, stream>>>(out, Wa, ntype, out, n);
}

// Round 3
// 390.895 us; speedup vs baseline: 4.0612x; 4.0612x over previous
//
#include <hip/hip_runtime.h>

#define D 128
#define TILE 32
#define SCAN_ELEMS 1024   // elements per scan1 block (256 thr x 4)

// ---------------------------------------------------------------------------
// Typed linear: Y[n,:] = X[n,:] @ W[ntype[n],:,:]   (X: [n,128], W: [2,128,128])
// Block: 256 threads, 32 nodes. Each thread: 4 nodes x 4 outs.
// ntype is sorted, so almost all blocks are type-uniform -> fast path.
// Safe in-place (Y == X): block reads its own 32 rows into LDS before writes.
// ---------------------------------------------------------------------------
__global__ __launch_bounds__(256) void typed_linear_kernel(
    const float* __restrict__ X, const float* __restrict__ W,
    const int* __restrict__ ntype, float* __restrict__ Y, int n)
{
    __shared__ float xs[TILE][D + 4];
    __shared__ float ws[2][TILE][D];

    const int t  = threadIdx.x;
    const int bn = blockIdx.x * TILE;

    #pragma unroll
    for (int i = 0; i < 4; ++i) {
        int idx  = t + i * 256;
        int node = idx >> 5;
        int c4   = idx & 31;
        float4 v = make_float4(0.f, 0.f, 0.f, 0.f);
        if (bn + node < n)
            v = reinterpret_cast<const float4*>(X)[(size_t)(bn + node) * (D / 4) + c4];
        *reinterpret_cast<float4*>(&xs[node][c4 * 4]) = v;
    }

    const int g  = t >> 5;
    const int oq = t & 31;

    const int last = (bn + TILE - 1 < n) ? bn + TILE - 1 : n - 1;
    const int tmin = ntype[bn];
    const int tmax = ntype[last];
    const bool uni = (tmin == tmax);

    int ty[4];
    #pragma unroll
    for (int i = 0; i < 4; ++i) {
        int node = bn + g * 4 + i;
        ty[i] = (node < n) ? ntype[node] : tmin;
    }

    float acc[4][4] = {};

    for (int kb = 0; kb < D; kb += TILE) {
        __syncthreads();
        if (uni) {
            #pragma unroll
            for (int i = 0; i < 4; ++i) {
                int idx = t + i * 256;
                int kk  = idx >> 5;
                int c4  = idx & 31;
                float4 w = reinterpret_cast<const float4*>(W)
                    [(size_t)tmin * (D * D / 4) + (size_t)(kb + kk) * (D / 4) + c4];
                *reinterpret_cast<float4*>(&ws[tmin][kk][c4 * 4]) = w;
            }
        } else {
            #pragma unroll
            for (int tt = 0; tt < 2; ++tt) {
                #pragma unroll
                for (int i = 0; i < 4; ++i) {
                    int idx = t + i * 256;
                    int kk  = idx >> 5;
                    int c4  = idx & 31;
                    float4 w = reinterpret_cast<const float4*>(W)
                        [(size_t)tt * (D * D / 4) + (size_t)(kb + kk) * (D / 4) + c4];
                    *reinterpret_cast<float4*>(&ws[tt][kk][c4 * 4]) = w;
                }
            }
        }
        __syncthreads();

        if (uni) {
            #pragma unroll
            for (int kk = 0; kk < TILE; ++kk) {
                float4 w = *reinterpret_cast<const float4*>(&ws[tmin][kk][oq * 4]);
                #pragma unroll
                for (int i = 0; i < 4; ++i) {
                    float xv = xs[g * 4 + i][kb + kk];
                    acc[i][0] += xv * w.x;
                    acc[i][1] += xv * w.y;
                    acc[i][2] += xv * w.z;
                    acc[i][3] += xv * w.w;
                }
            }
        } else {
            #pragma unroll
            for (int kk = 0; kk < TILE; ++kk) {
                #pragma unroll
                for (int i = 0; i < 4; ++i) {
                    float xv = xs[g * 4 + i][kb + kk];
                    float4 w = *reinterpret_cast<const float4*>(&ws[ty[i]][kk][oq * 4]);
                    acc[i][0] += xv * w.x;
                    acc[i][1] += xv * w.y;
                    acc[i][2] += xv * w.z;
                    acc[i][3] += xv * w.w;
                }
            }
        }
    }

    #pragma unroll
    for (int i = 0; i < 4; ++i) {
        int node = bn + g * 4 + i;
        if (node < n)
            reinterpret_cast<float4*>(Y)[(size_t)node * (D / 4) + oq] =
                make_float4(acc[i][0], acc[i][1], acc[i][2], acc[i][3]);
    }
}

// ---------------------------------------------------------------------------
// Counting sort of edges by dst, then per-node gather-sum (no f32 atomics).
// ---------------------------------------------------------------------------
__global__ __launch_bounds__(256) void hist_kernel(
    const int* __restrict__ dst, int* __restrict__ counts, int ne)
{
    int stride = gridDim.x * blockDim.x;
    for (int e = blockIdx.x * blockDim.x + threadIdx.x; e < ne; e += stride)
        atomicAdd(&counts[dst[e]], 1);
}

// scan1: per-block (1024 elems) exclusive scan; block totals to bsums.
__global__ __launch_bounds__(256) void scan1_kernel(
    const int* __restrict__ counts, int* __restrict__ offs,
    int* __restrict__ bsums, int n)
{
    __shared__ int lds[256];
    const int t    = threadIdx.x;
    const int base = blockIdx.x * SCAN_ELEMS + t * 4;

    int c[4]; int sum = 0;
    #pragma unroll
    for (int i = 0; i < 4; ++i) {
        c[i] = (base + i < n) ? counts[base + i] : 0;
        sum += c[i];
    }
    lds[t] = sum;
    __syncthreads();
    // Hillis-Steele inclusive scan over 256 thread sums
    for (int off = 1; off < 256; off <<= 1) {
        int x = (t >= off) ? lds[t - off] : 0;
        __syncthreads();
        lds[t] += x;
        __syncthreads();
    }
    int run = (t == 0) ? 0 : lds[t - 1];
    #pragma unroll
    for (int i = 0; i < 4; ++i) {
        if (base + i < n) offs[base + i] = run;
        run += c[i];
    }
    if (t == 255) bsums[blockIdx.x] = lds[255];
}

// scan2: single block, exclusive scan of up to 1024 block sums in-place.
__global__ __launch_bounds__(256) void scan2_kernel(int* __restrict__ bsums, int nb)
{
    __shared__ int lds[256];
    const int t    = threadIdx.x;
    const int base = t * 4;
    int c[4]; int sum = 0;
    #pragma unroll
    for (int i = 0; i < 4; ++i) {
        c[i] = (base + i < nb) ? bsums[base + i] : 0;
        sum += c[i];
    }
    lds[t] = sum;
    __syncthreads();
    for (int off = 1; off < 256; off <<= 1) {
        int x = (t >= off) ? lds[t - off] : 0;
        __syncthreads();
        lds[t] += x;
        __syncthreads();
    }
    int run = (t == 0) ? 0 : lds[t - 1];
    #pragma unroll
    for (int i = 0; i < 4; ++i) {
        if (base + i < nb) bsums[base + i] = run;
        run += c[i];
    }
}

// scan3: add block prefix; init cursor = offs.
__global__ __launch_bounds__(256) void scan3_kernel(
    int* __restrict__ offs, int* __restrict__ cursor,
    const int* __restrict__ bsums, int n)
{
    int i = blockIdx.x * blockDim.x + threadIdx.x;
    if (i < n) {
        int o = offs[i] + bsums[i / SCAN_ELEMS];
        offs[i]   = o;
        cursor[i] = o;
    }
}

// place: sorted_src[pos] = src[e], pos allocated via per-dst cursor.
__global__ __launch_bounds__(256) void place_kernel(
    const int* __restrict__ src, const int* __restrict__ dst,
    int* __restrict__ cursor, int* __restrict__ ssrc, int ne)
{
    int stride = gridDim.x * blockDim.x;
    for (int e = blockIdx.x * blockDim.x + threadIdx.x; e < ne; e += stride) {
        int d   = dst[e];
        int pos = atomicAdd(&cursor[d], 1);
        ssrc[pos] = src[e];
    }
}

// gather: one wave (64 lanes) per node; float2 per lane; plain store.
__global__ __launch_bounds__(256) void gather_kernel(
    const float* __restrict__ V, const int* __restrict__ offs,
    const int* __restrict__ counts, const int* __restrict__ ssrc,
    float* __restrict__ H, int n)
{
    const int wid  = (int)((blockIdx.x * 256 + threadIdx.x) >> 6);
    const int lane = threadIdx.x & 63;
    if (wid >= n) return;

    const int beg = offs[wid];
    const int cnt = counts[wid];
    const float2* V2 = reinterpret_cast<const float2*>(V);

    float2 acc = make_float2(0.f, 0.f);
    int j = 0;
    for (; j + 1 < cnt; j += 2) {
        int s0 = ssrc[beg + j];
        int s1 = ssrc[beg + j + 1];
        float2 a = V2[(size_t)s0 * 64 + lane];
        float2 b = V2[(size_t)s1 * 64 + lane];
        acc.x += a.x + b.x;
        acc.y += a.y + b.y;
    }
    if (j < cnt) {
        int s = ssrc[beg + j];
        float2 a = V2[(size_t)s * 64 + lane];
        acc.x += a.x;
        acc.y += a.y;
    }
    reinterpret_cast<float2*>(H)[(size_t)wid * 64 + lane] = acc;
}

// ---------------------------------------------------------------------------
extern "C" void kernel_launch(void* const* d_in, const int* in_sizes, int n_in,
                              void* d_out, int out_size, void* d_ws, size_t ws_size,
                              hipStream_t stream)
{
    const float* x     = (const float*)d_in[0];
    const int*   ntype = (const int*)d_in[1];
    const int*   src   = (const int*)d_in[2];
    const int*   dst   = (const int*)d_in[3];
    const float* Wv    = (const float*)d_in[4];
    const float* Wa    = (const float*)d_in[5];

    const int n  = in_sizes[0] / D;   // 100000 nodes
    const int ne = in_sizes[2];       // 800000 edges

    // workspace layout (256B-aligned chunks)
    char* ws = (char*)d_ws;
    size_t off = 0;
    auto alloc = [&](size_t bytes) {
        void* p = ws + off;
        off += (bytes + 255) & ~(size_t)255;
        return p;
    };
    float* v      = (float*)alloc((size_t)n * D * sizeof(float));
    int*   counts = (int*)  alloc((size_t)n * sizeof(int));
    int*   offs   = (int*)  alloc((size_t)n * sizeof(int));
    int*   cursor = (int*)  alloc((size_t)n * sizeof(int));
    int*   bsums  = (int*)  alloc(1024 * sizeof(int));
    int*   ssrc   = (int*)  alloc((size_t)ne * sizeof(int));

    float* out = (float*)d_out;

    hipMemsetAsync(counts, 0, (size_t)n * sizeof(int), stream);

    // stage 1: v = typed_linear(x, W_v)
    const int nblk = (n + TILE - 1) / TILE;
    typed_linear_kernel<<<nblk, 256, 0, stream>>>(x, Wv, ntype, v, n);

    // counting sort of edges by dst
    hist_kernel<<<1024, 256, 0, stream>>>(dst, counts, ne);
    const int nb = (n + SCAN_ELEMS - 1) / SCAN_ELEMS;      // 98 for n=100000
    scan1_kernel<<<nb, 256, 0, stream>>>(counts, offs, bsums, n);
    scan2_kernel<<<1, 256, 0, stream>>>(bsums, nb);
    scan3_kernel<<<(n + 255) / 256, 256, 0, stream>>>(offs, cursor, bsums, n);
    place_kernel<<<1024, 256, 0, stream>>>(src, dst, cursor, ssrc, ne);

    // stage 2: h = segment-sum (gather over sorted edges), h -> d_out
    const int gblk = (n * 64 + 255) / 256;   // one wave per node
    gather_kernel<<<gblk, 256, 0, stream>>>(v, offs, counts, ssrc, out, n);

    // stage 3: out = typed_linear(h, W_a), in-place
    typed_linear_kernel<<<nblk, 256, 0, stream>>>(out, Wa, ntype, out, n);
}

// Round 6
// 381.384 us; speedup vs baseline: 4.1625x; 1.0249x over previous
//
#include <hip/hip_runtime.h>

#define D 128
#define SCAN_ELEMS 1024   // elements per scan1 block (256 thr x 4)

typedef __attribute__((ext_vector_type(8))) __bf16 bf16x8;
typedef __attribute__((ext_vector_type(4))) float  f32x4;

// ---------------------------------------------------------------------------
// wprep: wt[m][col][k] = (bf16) W_m[k][col]   (m: 0,1 = Wv types; 2,3 = Wa)
// 4 x 128 x 128 bf16 = 128 KB, L2-resident; consumed broadcast by all blocks.
// ---------------------------------------------------------------------------
__global__ __launch_bounds__(256) void wprep_kernel(
    const float* __restrict__ Wv, const float* __restrict__ Wa,
    __bf16* __restrict__ wt)
{
    int idx = blockIdx.x * 256 + threadIdx.x;    // 0..65535
    int m   = idx >> 14;
    int col = (idx >> 7) & 127;
    int k   = idx & 127;
    const float* src = (m < 2) ? Wv + ((size_t)m * 128 + k) * 128 + col
                               : Wa + ((size_t)(m - 2) * 128 + k) * 128 + col;
    wt[idx] = (__bf16)(*src);   // write coalesced; reads are L2-absorbed
}

// ---------------------------------------------------------------------------
// Typed linear via MFMA: Y[r,:] = X[r,:] @ W[ntype[r]]   (bf16 in, f32 acc)
// Block: 256 thr = 4 waves, 64 rows. Wave w owns cols [w*32, w*32+32).
// B (W^T slice) held entirely in registers, loaded from L2 -> no LDS, no sync.
// In-place safe (Y==X): block reads only its own 64 rows; stores after k-loop.
// ntype sorted -> almost all blocks type-uniform; mixed runs 2 passes.
// ---------------------------------------------------------------------------
__global__ __launch_bounds__(256, 4) void typed_mfma_kernel(
    const float* __restrict__ X, const __bf16* __restrict__ WT,
    const int* __restrict__ ntype, float* __restrict__ Y, int n)
{
    const int tix = threadIdx.x;
    const int w   = tix >> 6;     // wave 0..3 -> n-slice
    const int l   = tix & 63;
    const int l15 = l & 15;
    const int lk  = l >> 4;       // 0..3
    const int bm  = blockIdx.x * 64;

    const int last = (bm + 63 < n) ? bm + 63 : n - 1;
    const int t0   = ntype[bm];
    const int t1   = ntype[last];
    const bool uni = (t0 == t1);

    for (int t = t0; t <= t1; ++t) {
        // B fragments: bfr[ks][nf] = W^T[col][ks*32 + lk*8 .. +8)
        const __bf16* wb = WT + ((size_t)t << 14);
        bf16x8 bfr[4][2];
        #pragma unroll
        for (int ks = 0; ks < 4; ++ks)
            #pragma unroll
            for (int nf = 0; nf < 2; ++nf) {
                int col = w * 32 + nf * 16 + l15;
                bfr[ks][nf] = *reinterpret_cast<const bf16x8*>(
                    wb + col * 128 + ks * 32 + lk * 8);
            }

        f32x4 acc[4][2];
        #pragma unroll
        for (int rg = 0; rg < 4; ++rg)
            #pragma unroll
            for (int nf = 0; nf < 2; ++nf)
                acc[rg][nf] = (f32x4){0.f, 0.f, 0.f, 0.f};

        #pragma unroll
        for (int rg = 0; rg < 4; ++rg) {
            int row = bm + rg * 16 + l15;
            if (row > n - 1) row = n - 1;          // clamp OOB (stores predicated)
            const float* xr = X + (size_t)row * D + lk * 8;
            #pragma unroll
            for (int ks = 0; ks < 4; ++ks) {
                float4 f0 = *reinterpret_cast<const float4*>(xr + ks * 32);
                float4 f1 = *reinterpret_cast<const float4*>(xr + ks * 32 + 4);
                bf16x8 a;
                a[0] = (__bf16)f0.x; a[1] = (__bf16)f0.y;
                a[2] = (__bf16)f0.z; a[3] = (__bf16)f0.w;
                a[4] = (__bf16)f1.x; a[5] = (__bf16)f1.y;
                a[6] = (__bf16)f1.z; a[7] = (__bf16)f1.w;
                acc[rg][0] = __builtin_amdgcn_mfma_f32_16x16x32_bf16(
                    a, bfr[ks][0], acc[rg][0], 0, 0, 0);
                acc[rg][1] = __builtin_amdgcn_mfma_f32_16x16x32_bf16(
                    a, bfr[ks][1], acc[rg][1], 0, 0, 0);
            }
        }

        // C/D layout (verified m89/m91): col = lane&15, row = (lane>>4)*4 + e
        #pragma unroll
        for (int rg = 0; rg < 4; ++rg)
            #pragma unroll
            for (int nf = 0; nf < 2; ++nf) {
                int c = w * 32 + nf * 16 + l15;
                #pragma unroll
                for (int e = 0; e < 4; ++e) {
                    int r = bm + rg * 16 + lk * 4 + e;
                    if (r < n && (uni || ntype[r] == t))
                        Y[(size_t)r * D + c] = acc[rg][nf][e];
                }
            }
    }
}

// ---------------------------------------------------------------------------
// Counting sort of edges by dst, then per-node gather-sum (no f32 atomics).
// ---------------------------------------------------------------------------
__global__ __launch_bounds__(256) void hist_kernel(
    const int* __restrict__ dst, int* __restrict__ counts, int ne)
{
    int stride = gridDim.x * blockDim.x;
    for (int e = blockIdx.x * blockDim.x + threadIdx.x; e < ne; e += stride)
        atomicAdd(&counts[dst[e]], 1);
}

__global__ __launch_bounds__(256) void scan1_kernel(
    const int* __restrict__ counts, int* __restrict__ offs,
    int* __restrict__ bsums, int n)
{
    __shared__ int lds[256];
    const int t    = threadIdx.x;
    const int base = blockIdx.x * SCAN_ELEMS + t * 4;

    int c[4]; int sum = 0;
    #pragma unroll
    for (int i = 0; i < 4; ++i) {
        c[i] = (base + i < n) ? counts[base + i] : 0;
        sum += c[i];
    }
    lds[t] = sum;
    __syncthreads();
    for (int off = 1; off < 256; off <<= 1) {
        int x = (t >= off) ? lds[t - off] : 0;
        __syncthreads();
        lds[t] += x;
        __syncthreads();
    }
    int run = (t == 0) ? 0 : lds[t - 1];
    #pragma unroll
    for (int i = 0; i < 4; ++i) {
        if (base + i < n) offs[base + i] = run;
        run += c[i];
    }
    if (t == 255) bsums[blockIdx.x] = lds[255];
}

__global__ __launch_bounds__(256) void scan2_kernel(int* __restrict__ bsums, int nb)
{
    __shared__ int lds[256];
    const int t    = threadIdx.x;
    const int base = t * 4;
    int c[4]; int sum = 0;
    #pragma unroll
    for (int i = 0; i < 4; ++i) {
        c[i] = (base + i < nb) ? bsums[base + i] : 0;
        sum += c[i];
    }
    lds[t] = sum;
    __syncthreads();
    for (int off = 1; off < 256; off <<= 1) {
        int x = (t >= off) ? lds[t - off] : 0;
        __syncthreads();
        lds[t] += x;
        __syncthreads();
    }
    int run = (t == 0) ? 0 : lds[t - 1];
    #pragma unroll
    for (int i = 0; i < 4; ++i) {
        if (base + i < nb) bsums[base + i] = run;
        run += c[i];
    }
}

__global__ __launch_bounds__(256) void scan3_kernel(
    int* __restrict__ offs, int* __restrict__ cursor,
    const int* __restrict__ bsums, int n)
{
    int i = blockIdx.x * blockDim.x + threadIdx.x;
    if (i < n) {
        int o = offs[i] + bsums[i / SCAN_ELEMS];
        offs[i]   = o;
        cursor[i] = o;
    }
}

__global__ __launch_bounds__(256) void place_kernel(
    const int* __restrict__ src, const int* __restrict__ dst,
    int* __restrict__ cursor, int* __restrict__ ssrc, int ne)
{
    int stride = gridDim.x * blockDim.x;
    for (int e = blockIdx.x * blockDim.x + threadIdx.x; e < ne; e += stride) {
        int d   = dst[e];
        int pos = atomicAdd(&cursor[d], 1);
        ssrc[pos] = src[e];
    }
}

// gather: one wave (64 lanes) per node; float2 per lane; plain store.
// Writes EVERY node row (zeros for isolated nodes) -> no d_out memset needed.
__global__ __launch_bounds__(256) void gather_kernel(
    const float* __restrict__ V, const int* __restrict__ offs,
    const int* __restrict__ counts, const int* __restrict__ ssrc,
    float* __restrict__ H, int n)
{
    const int wid  = (int)((blockIdx.x * 256 + threadIdx.x) >> 6);
    const int lane = threadIdx.x & 63;
    if (wid >= n) return;

    const int beg = offs[wid];
    const int cnt = counts[wid];
    const float2* V2 = reinterpret_cast<const float2*>(V);

    float2 acc = make_float2(0.f, 0.f);
    int j = 0;
    for (; j + 1 < cnt; j += 2) {
        int s0 = ssrc[beg + j];
        int s1 = ssrc[beg + j + 1];
        float2 a = V2[(size_t)s0 * 64 + lane];
        float2 b = V2[(size_t)s1 * 64 + lane];
        acc.x += a.x + b.x;
        acc.y += a.y + b.y;
    }
    if (j < cnt) {
        int s = ssrc[beg + j];
        float2 a = V2[(size_t)s * 64 + lane];
        acc.x += a.x;
        acc.y += a.y;
    }
    reinterpret_cast<float2*>(H)[(size_t)wid * 64 + lane] = acc;
}

// ---------------------------------------------------------------------------
extern "C" void kernel_launch(void* const* d_in, const int* in_sizes, int n_in,
                              void* d_out, int out_size, void* d_ws, size_t ws_size,
                              hipStream_t stream)
{
    const float* x     = (const float*)d_in[0];
    const int*   ntype = (const int*)d_in[1];
    const int*   src   = (const int*)d_in[2];
    const int*   dst   = (const int*)d_in[3];
    const float* Wv    = (const float*)d_in[4];
    const float* Wa    = (const float*)d_in[5];

    const int n  = in_sizes[0] / D;   // 100000 nodes
    const int ne = in_sizes[2];       // 800000 edges

    // workspace layout (256B-aligned chunks)
    char* ws = (char*)d_ws;
    size_t off = 0;
    auto alloc = [&](size_t bytes) {
        void* p = ws + off;
        off += (bytes + 255) & ~(size_t)255;
        return p;
    };
    float*  v      = (float*) alloc((size_t)n * D * sizeof(float));
    __bf16* wt     = (__bf16*)alloc((size_t)4 * 128 * 128 * sizeof(__bf16));
    int*    counts = (int*)   alloc((size_t)n * sizeof(int));
    int*    offs   = (int*)   alloc((size_t)n * sizeof(int));
    int*    cursor = (int*)   alloc((size_t)n * sizeof(int));
    int*    bsums  = (int*)   alloc(1024 * sizeof(int));
    int*    ssrc   = (int*)   alloc((size_t)ne * sizeof(int));

    float* out = (float*)d_out;

    hipMemsetAsync(counts, 0, (size_t)n * sizeof(int), stream);

    // prep: transposed bf16 weights (Wv -> wt[0..1], Wa -> wt[2..3])
    wprep_kernel<<<256, 256, 0, stream>>>(Wv, Wa, wt);

    // stage 1: v = typed_linear(x, W_v)  [MFMA]
    const int nblk = (n + 63) / 64;
    typed_mfma_kernel<<<nblk, 256, 0, stream>>>(x, wt, ntype, v, n);

    // counting sort of edges by dst
    hist_kernel<<<1024, 256, 0, stream>>>(dst, counts, ne);
    const int nb = (n + SCAN_ELEMS - 1) / SCAN_ELEMS;
    scan1_kernel<<<nb, 256, 0, stream>>>(counts, offs, bsums, n);
    scan2_kernel<<<1, 256, 0, stream>>>(bsums, nb);
    scan3_kernel<<<(n + 255) / 256, 256, 0, stream>>>(offs, cursor, bsums, n);
    place_kernel<<<1024, 256, 0, stream>>>(src, dst, cursor, ssrc, ne);

    // stage 2: h = segment-sum (gather over sorted edges) -> d_out
    const int gblk = (n * 64 + 255) / 256;
    gather_kernel<<<gblk, 256, 0, stream>>>(v, offs, counts, ssrc, out, n);

    // stage 3: out = typed_linear(h, W_a)  [MFMA, in-place]
    typed_mfma_kernel<<<nblk, 256, 0, stream>>>(out, wt + 2 * 128 * 128, ntype, out, n);
}

// Round 7
// 356.745 us; speedup vs baseline: 4.4500x; 1.0691x over previous
//
#include <hip/hip_runtime.h>

#define D 128
#define SCAN_ELEMS 1024   // elements per scan1 block (256 thr x 4)

typedef __attribute__((ext_vector_type(8))) __bf16 bf16x8;
typedef __attribute__((ext_vector_type(4))) float  f32x4;

// ---------------------------------------------------------------------------
// wprep: wt[m][col][k] = (bf16) W_m[k][col]   (m: 0,1 = Wv types; 2,3 = Wa)
// 4 x 128 x 128 bf16 = 128 KB, L2-resident; consumed broadcast by all blocks.
// ---------------------------------------------------------------------------
__global__ __launch_bounds__(256) void wprep_kernel(
    const float* __restrict__ Wv, const float* __restrict__ Wa,
    __bf16* __restrict__ wt)
{
    int idx = blockIdx.x * 256 + threadIdx.x;    // 0..65535
    int m   = idx >> 14;
    int col = (idx >> 7) & 127;
    int k   = idx & 127;
    const float* src = (m < 2) ? Wv + ((size_t)m * 128 + k) * 128 + col
                               : Wa + ((size_t)(m - 2) * 128 + k) * 128 + col;
    wt[idx] = (__bf16)(*src);
}

// ---------------------------------------------------------------------------
// Typed linear via MFMA, v2: swapped operands + LDS epilogue.
//   mfma(A=W^T frag, B=X frag) -> D = Y^T fragments: lane holds one output
//   row (l&15) x 4 consecutive cols ((l>>4)*4+e) -> float4 into LDS, then
//   linear float4 copy-out (full 128B lines, no RMW write amplification).
// Block: 256 thr = 4 waves, 64 rows; wave w owns cols [w*32, w*32+32).
// In-place safe (Y==X): all X reads complete before first barrier; stores
// only to own rows. ntype sorted -> almost all blocks uniform.
// ---------------------------------------------------------------------------
__global__ __launch_bounds__(256, 4) void typed_mfma_kernel(
    const float* __restrict__ X, const __bf16* __restrict__ WT,
    const int* __restrict__ ntype, float* __restrict__ Y, int n)
{
    __shared__ float lds_y[32 * 132];   // one 32-row chunk, +4 pad per row

    const int tix = threadIdx.x;
    const int w   = tix >> 6;     // wave 0..3 -> col-slice
    const int l   = tix & 63;
    const int l15 = l & 15;
    const int lk  = l >> 4;       // 0..3
    const int bm  = blockIdx.x * 64;

    const int last = (bm + 63 < n) ? bm + 63 : n - 1;
    const int t0   = ntype[bm];
    const int t1   = ntype[last];
    const bool uni = (t0 == t1);

    for (int t = t0; t <= t1; ++t) {
        // W^T fragments (A-operand): wfr[ks][nf] = W^T[col][ks*32+lk*8 ..+8)
        const __bf16* wb = WT + ((size_t)t << 14);
        bf16x8 wfr[4][2];
        #pragma unroll
        for (int ks = 0; ks < 4; ++ks)
            #pragma unroll
            for (int nf = 0; nf < 2; ++nf) {
                int col = w * 32 + nf * 16 + l15;
                wfr[ks][nf] = *reinterpret_cast<const bf16x8*>(
                    wb + col * 128 + ks * 32 + lk * 8);
            }

        f32x4 acc[4][2];
        #pragma unroll
        for (int rg = 0; rg < 4; ++rg)
            #pragma unroll
            for (int nf = 0; nf < 2; ++nf)
                acc[rg][nf] = (f32x4){0.f, 0.f, 0.f, 0.f};

        #pragma unroll
        for (int rg = 0; rg < 4; ++rg) {
            int row = bm + rg * 16 + l15;
            if (row > n - 1) row = n - 1;          // only last block clamps
            const float* xr = X + (size_t)row * D + lk * 8;
            #pragma unroll
            for (int ks = 0; ks < 4; ++ks) {
                float4 f0 = *reinterpret_cast<const float4*>(xr + ks * 32);
                float4 f1 = *reinterpret_cast<const float4*>(xr + ks * 32 + 4);
                bf16x8 a;
                a[0] = (__bf16)f0.x; a[1] = (__bf16)f0.y;
                a[2] = (__bf16)f0.z; a[3] = (__bf16)f0.w;
                a[4] = (__bf16)f1.x; a[5] = (__bf16)f1.y;
                a[6] = (__bf16)f1.z; a[7] = (__bf16)f1.w;
                // swapped: D = W^T x X^T = Y^T
                acc[rg][0] = __builtin_amdgcn_mfma_f32_16x16x32_bf16(
                    wfr[ks][0], a, acc[rg][0], 0, 0, 0);
                acc[rg][1] = __builtin_amdgcn_mfma_f32_16x16x32_bf16(
                    wfr[ks][1], a, acc[rg][1], 0, 0, 0);
            }
        }

        // epilogue: two 32-row chunks through LDS, coalesced float4 out
        #pragma unroll
        for (int ch = 0; ch < 2; ++ch) {
            __syncthreads();   // all X reads + prior chunk copy-out done
            #pragma unroll
            for (int rh = 0; rh < 2; ++rh) {
                int rg = ch * 2 + rh;
                #pragma unroll
                for (int nf = 0; nf < 2; ++nf) {
                    int rloc = rh * 16 + l15;
                    int c    = w * 32 + nf * 16 + lk * 4;
                    *reinterpret_cast<float4*>(&lds_y[rloc * 132 + c]) =
                        make_float4(acc[rg][nf][0], acc[rg][nf][1],
                                    acc[rg][nf][2], acc[rg][nf][3]);
                }
            }
            __syncthreads();
            #pragma unroll
            for (int p = 0; p < 4; ++p) {
                int idx = tix + p * 256;
                int rr  = idx >> 5;
                int c4  = idx & 31;
                int row = bm + ch * 32 + rr;
                if (row < n && (uni || ntype[row] == t)) {
                    float4 val = *reinterpret_cast<const float4*>(
                        &lds_y[rr * 132 + c4 * 4]);
                    *reinterpret_cast<float4*>(&Y[(size_t)row * D + c4 * 4]) = val;
                }
            }
        }
    }
}

// ---------------------------------------------------------------------------
// Counting sort of edges by dst, then per-node gather-sum (no f32 atomics).
// ---------------------------------------------------------------------------
__global__ __launch_bounds__(256) void hist_kernel(
    const int* __restrict__ dst, int* __restrict__ counts, int ne)
{
    int stride = gridDim.x * blockDim.x;
    for (int e = blockIdx.x * blockDim.x + threadIdx.x; e < ne; e += stride)
        atomicAdd(&counts[dst[e]], 1);
}

__global__ __launch_bounds__(256) void scan1_kernel(
    const int* __restrict__ counts, int* __restrict__ offs,
    int* __restrict__ bsums, int n)
{
    __shared__ int lds[256];
    const int t    = threadIdx.x;
    const int base = blockIdx.x * SCAN_ELEMS + t * 4;

    int c[4]; int sum = 0;
    #pragma unroll
    for (int i = 0; i < 4; ++i) {
        c[i] = (base + i < n) ? counts[base + i] : 0;
        sum += c[i];
    }
    lds[t] = sum;
    __syncthreads();
    for (int off = 1; off < 256; off <<= 1) {
        int x = (t >= off) ? lds[t - off] : 0;
        __syncthreads();
        lds[t] += x;
        __syncthreads();
    }
    int run = (t == 0) ? 0 : lds[t - 1];
    #pragma unroll
    for (int i = 0; i < 4; ++i) {
        if (base + i < n) offs[base + i] = run;
        run += c[i];
    }
    if (t == 255) bsums[blockIdx.x] = lds[255];
}

__global__ __launch_bounds__(256) void scan2_kernel(int* __restrict__ bsums, int nb)
{
    __shared__ int lds[256];
    const int t    = threadIdx.x;
    const int base = t * 4;
    int c[4]; int sum = 0;
    #pragma unroll
    for (int i = 0; i < 4; ++i) {
        c[i] = (base + i < nb) ? bsums[base + i] : 0;
        sum += c[i];
    }
    lds[t] = sum;
    __syncthreads();
    for (int off = 1; off < 256; off <<= 1) {
        int x = (t >= off) ? lds[t - off] : 0;
        __syncthreads();
        lds[t] += x;
        __syncthreads();
    }
    int run = (t == 0) ? 0 : lds[t - 1];
    #pragma unroll
    for (int i = 0; i < 4; ++i) {
        if (base + i < nb) bsums[base + i] = run;
        run += c[i];
    }
}

__global__ __launch_bounds__(256) void scan3_kernel(
    int* __restrict__ offs, int* __restrict__ cursor,
    const int* __restrict__ bsums, int n)
{
    int i = blockIdx.x * blockDim.x + threadIdx.x;
    if (i < n) {
        int o = offs[i] + bsums[i / SCAN_ELEMS];
        offs[i]   = o;
        cursor[i] = o;
    }
}

__global__ __launch_bounds__(256) void place_kernel(
    const int* __restrict__ src, const int* __restrict__ dst,
    int* __restrict__ cursor, int* __restrict__ ssrc, int ne)
{
    int stride = gridDim.x * blockDim.x;
    for (int e = blockIdx.x * blockDim.x + threadIdx.x; e < ne; e += stride) {
        int d   = dst[e];
        int pos = atomicAdd(&cursor[d], 1);
        ssrc[pos] = src[e];
    }
}

// gather: one wave (64 lanes) per node; float2 per lane; plain store.
// Writes EVERY node row (zeros for isolated nodes) -> no d_out memset needed.
__global__ __launch_bounds__(256) void gather_kernel(
    const float* __restrict__ V, const int* __restrict__ offs,
    const int* __restrict__ counts, const int* __restrict__ ssrc,
    float* __restrict__ H, int n)
{
    const int wid  = (int)((blockIdx.x * 256 + threadIdx.x) >> 6);
    const int lane = threadIdx.x & 63;
    if (wid >= n) return;

    const int beg = offs[wid];
    const int cnt = counts[wid];
    const float2* V2 = reinterpret_cast<const float2*>(V);

    float2 acc = make_float2(0.f, 0.f);
    int j = 0;
    for (; j + 1 < cnt; j += 2) {
        int s0 = ssrc[beg + j];
        int s1 = ssrc[beg + j + 1];
        float2 a = V2[(size_t)s0 * 64 + lane];
        float2 b = V2[(size_t)s1 * 64 + lane];
        acc.x += a.x + b.x;
        acc.y += a.y + b.y;
    }
    if (j < cnt) {
        int s = ssrc[beg + j];
        float2 a = V2[(size_t)s * 64 + lane];
        acc.x += a.x;
        acc.y += a.y;
    }
    reinterpret_cast<float2*>(H)[(size_t)wid * 64 + lane] = acc;
}

// ---------------------------------------------------------------------------
extern "C" void kernel_launch(void* const* d_in, const int* in_sizes, int n_in,
                              void* d_out, int out_size, void* d_ws, size_t ws_size,
                              hipStream_t stream)
{
    const float* x     = (const float*)d_in[0];
    const int*   ntype = (const int*)d_in[1];
    const int*   src   = (const int*)d_in[2];
    const int*   dst   = (const int*)d_in[3];
    const float* Wv    = (const float*)d_in[4];
    const float* Wa    = (const float*)d_in[5];

    const int n  = in_sizes[0] / D;   // 100000 nodes
    const int ne = in_sizes[2];       // 800000 edges

    // workspace layout (256B-aligned chunks)
    char* ws = (char*)d_ws;
    size_t off = 0;
    auto alloc = [&](size_t bytes) {
        void* p = ws + off;
        off += (bytes + 255) & ~(size_t)255;
        return p;
    };
    float*  v      = (float*) alloc((size_t)n * D * sizeof(float));
    __bf16* wt     = (__bf16*)alloc((size_t)4 * 128 * 128 * sizeof(__bf16));
    int*    counts = (int*)   alloc((size_t)n * sizeof(int));
    int*    offs   = (int*)   alloc((size_t)n * sizeof(int));
    int*    cursor = (int*)   alloc((size_t)n * sizeof(int));
    int*    bsums  = (int*)   alloc(1024 * sizeof(int));
    int*    ssrc   = (int*)   alloc((size_t)ne * sizeof(int));

    float* out = (float*)d_out;

    hipMemsetAsync(counts, 0, (size_t)n * sizeof(int), stream);

    // prep: transposed bf16 weights (Wv -> wt[0..1], Wa -> wt[2..3])
    wprep_kernel<<<256, 256, 0, stream>>>(Wv, Wa, wt);

    // stage 1: v = typed_linear(x, W_v)  [MFMA]
    const int nblk = (n + 63) / 64;
    typed_mfma_kernel<<<nblk, 256, 0, stream>>>(x, wt, ntype, v, n);

    // counting sort of edges by dst
    hist_kernel<<<1024, 256, 0, stream>>>(dst, counts, ne);
    const int nb = (n + SCAN_ELEMS - 1) / SCAN_ELEMS;
    scan1_kernel<<<nb, 256, 0, stream>>>(counts, offs, bsums, n);
    scan2_kernel<<<1, 256, 0, stream>>>(bsums, nb);
    scan3_kernel<<<(n + 255) / 256, 256, 0, stream>>>(offs, cursor, bsums, n);
    place_kernel<<<1024, 256, 0, stream>>>(src, dst, cursor, ssrc, ne);

    // stage 2: h = segment-sum (gather over sorted edges) -> d_out
    const int gblk = (n * 64 + 255) / 256;
    gather_kernel<<<gblk, 256, 0, stream>>>(v, offs, counts, ssrc, out, n);

    // stage 3: out = typed_linear(h, W_a)  [MFMA, in-place]
    typed_mfma_kernel<<<nblk, 256, 0, stream>>>(out, wt + 2 * 128 * 128, ntype, out, n);
}

// Round 8
// 304.540 us; speedup vs baseline: 5.2129x; 1.1714x over previous
//
#include <hip/hip_runtime.h>

#define D 128
#define SCAN_ELEMS 1024   // elements per scan1 block (256 thr x 4)

typedef __attribute__((ext_vector_type(8))) __bf16 bf16x8;
typedef __attribute__((ext_vector_type(4))) __bf16 bf16x4;
typedef __attribute__((ext_vector_type(2))) __bf16 bf16x2;
typedef __attribute__((ext_vector_type(4))) float  f32x4;

// ---------------------------------------------------------------------------
// wprep: wt[m][col][k] = (bf16) W_m[k][col]   (m: 0,1 = Wv types; 2,3 = Wa)
// 4 x 128 x 128 bf16 = 128 KB, L2/L3-resident.
// ---------------------------------------------------------------------------
__global__ __launch_bounds__(256) void wprep_kernel(
    const float* __restrict__ Wv, const float* __restrict__ Wa,
    __bf16* __restrict__ wt)
{
    int idx = blockIdx.x * 256 + threadIdx.x;    // 0..65535
    int m   = idx >> 14;
    int col = (idx >> 7) & 127;
    int k   = idx & 127;
    const float* src = (m < 2) ? Wv + ((size_t)m * 128 + k) * 128 + col
                               : Wa + ((size_t)(m - 2) * 128 + k) * 128 + col;
    wt[idx] = (__bf16)(*src);
}

// ---------------------------------------------------------------------------
// Stage 1: V[r,:] = (bf16) X[r,:] @ W_v[ntype[r]]   (X f32 in, V bf16 out)
// Swapped-operand MFMA (D = Y^T frags: lane = 1 row x 4 cols) + LDS epilogue
// -> fully-coalesced bf16x8 stores (256 B per row, no RMW).
// Block: 256 thr = 4 waves, 64 rows; wave w owns cols [w*32, w*32+32).
// ---------------------------------------------------------------------------
__global__ __launch_bounds__(256, 4) void typed_mfma_f32_bf16(
    const float* __restrict__ X, const __bf16* __restrict__ WT,
    const int* __restrict__ ntype, __bf16* __restrict__ V, int n)
{
    __shared__ __bf16 lds_v[32 * 136];   // 32-row chunk, +8 bf16 pad per row

    const int tix = threadIdx.x;
    const int w   = tix >> 6;
    const int l   = tix & 63;
    const int l15 = l & 15;
    const int lk  = l >> 4;
    const int bm  = blockIdx.x * 64;

    const int last = (bm + 63 < n) ? bm + 63 : n - 1;
    const int t0   = ntype[bm];
    const int t1   = ntype[last];
    const bool uni = (t0 == t1);

    for (int t = t0; t <= t1; ++t) {
        const __bf16* wb = WT + ((size_t)t << 14);
        bf16x8 wfr[4][2];
        #pragma unroll
        for (int ks = 0; ks < 4; ++ks)
            #pragma unroll
            for (int nf = 0; nf < 2; ++nf) {
                int col = w * 32 + nf * 16 + l15;
                wfr[ks][nf] = *reinterpret_cast<const bf16x8*>(
                    wb + col * 128 + ks * 32 + lk * 8);
            }

        f32x4 acc[4][2];
        #pragma unroll
        for (int rg = 0; rg < 4; ++rg)
            #pragma unroll
            for (int nf = 0; nf < 2; ++nf)
                acc[rg][nf] = (f32x4){0.f, 0.f, 0.f, 0.f};

        #pragma unroll
        for (int rg = 0; rg < 4; ++rg) {
            int row = bm + rg * 16 + l15;
            if (row > n - 1) row = n - 1;
            const float* xr = X + (size_t)row * D + lk * 8;
            #pragma unroll
            for (int ks = 0; ks < 4; ++ks) {
                float4 f0 = *reinterpret_cast<const float4*>(xr + ks * 32);
                float4 f1 = *reinterpret_cast<const float4*>(xr + ks * 32 + 4);
                bf16x8 a;
                a[0] = (__bf16)f0.x; a[1] = (__bf16)f0.y;
                a[2] = (__bf16)f0.z; a[3] = (__bf16)f0.w;
                a[4] = (__bf16)f1.x; a[5] = (__bf16)f1.y;
                a[6] = (__bf16)f1.z; a[7] = (__bf16)f1.w;
                acc[rg][0] = __builtin_amdgcn_mfma_f32_16x16x32_bf16(
                    wfr[ks][0], a, acc[rg][0], 0, 0, 0);
                acc[rg][1] = __builtin_amdgcn_mfma_f32_16x16x32_bf16(
                    wfr[ks][1], a, acc[rg][1], 0, 0, 0);
            }
        }

        #pragma unroll
        for (int ch = 0; ch < 2; ++ch) {
            __syncthreads();
            #pragma unroll
            for (int rh = 0; rh < 2; ++rh) {
                int rg = ch * 2 + rh;
                #pragma unroll
                for (int nf = 0; nf < 2; ++nf) {
                    int rloc = rh * 16 + l15;
                    int c    = w * 32 + nf * 16 + lk * 4;
                    bf16x4 o;
                    o[0] = (__bf16)acc[rg][nf][0];
                    o[1] = (__bf16)acc[rg][nf][1];
                    o[2] = (__bf16)acc[rg][nf][2];
                    o[3] = (__bf16)acc[rg][nf][3];
                    *reinterpret_cast<bf16x4*>(&lds_v[rloc * 136 + c]) = o;
                }
            }
            __syncthreads();
            #pragma unroll
            for (int p = 0; p < 2; ++p) {
                int idx = tix + p * 256;          // 0..511 = 32 rows x 16 col8
                int rr  = idx >> 4;
                int c8  = idx & 15;
                int row = bm + ch * 32 + rr;
                if (row < n && (uni || ntype[row] == t)) {
                    bf16x8 val = *reinterpret_cast<const bf16x8*>(
                        &lds_v[rr * 136 + c8 * 8]);
                    *reinterpret_cast<bf16x8*>(&V[(size_t)row * D + c8 * 8]) = val;
                }
            }
        }
    }
}

// ---------------------------------------------------------------------------
// Stage 3: Y[r,:] = H[r,:] @ W_a[ntype[r]]   (H bf16 in, Y f32 out)
// A-fragments load directly as bf16x8 (no cvt). f32 LDS epilogue (round-7).
// ---------------------------------------------------------------------------
__global__ __launch_bounds__(256, 4) void typed_mfma_bf16_f32(
    const __bf16* __restrict__ H, const __bf16* __restrict__ WT,
    const int* __restrict__ ntype, float* __restrict__ Y, int n)
{
    __shared__ float lds_y[32 * 132];

    const int tix = threadIdx.x;
    const int w   = tix >> 6;
    const int l   = tix & 63;
    const int l15 = l & 15;
    const int lk  = l >> 4;
    const int bm  = blockIdx.x * 64;

    const int last = (bm + 63 < n) ? bm + 63 : n - 1;
    const int t0   = ntype[bm];
    const int t1   = ntype[last];
    const bool uni = (t0 == t1);

    for (int t = t0; t <= t1; ++t) {
        const __bf16* wb = WT + ((size_t)t << 14);
        bf16x8 wfr[4][2];
        #pragma unroll
        for (int ks = 0; ks < 4; ++ks)
            #pragma unroll
            for (int nf = 0; nf < 2; ++nf) {
                int col = w * 32 + nf * 16 + l15;
                wfr[ks][nf] = *reinterpret_cast<const bf16x8*>(
                    wb + col * 128 + ks * 32 + lk * 8);
            }

        f32x4 acc[4][2];
        #pragma unroll
        for (int rg = 0; rg < 4; ++rg)
            #pragma unroll
            for (int nf = 0; nf < 2; ++nf)
                acc[rg][nf] = (f32x4){0.f, 0.f, 0.f, 0.f};

        #pragma unroll
        for (int rg = 0; rg < 4; ++rg) {
            int row = bm + rg * 16 + l15;
            if (row > n - 1) row = n - 1;
            const __bf16* hr = H + (size_t)row * D + lk * 8;
            #pragma unroll
            for (int ks = 0; ks < 4; ++ks) {
                bf16x8 a = *reinterpret_cast<const bf16x8*>(hr + ks * 32);
                acc[rg][0] = __builtin_amdgcn_mfma_f32_16x16x32_bf16(
                    wfr[ks][0], a, acc[rg][0], 0, 0, 0);
                acc[rg][1] = __builtin_amdgcn_mfma_f32_16x16x32_bf16(
                    wfr[ks][1], a, acc[rg][1], 0, 0, 0);
            }
        }

        #pragma unroll
        for (int ch = 0; ch < 2; ++ch) {
            __syncthreads();
            #pragma unroll
            for (int rh = 0; rh < 2; ++rh) {
                int rg = ch * 2 + rh;
                #pragma unroll
                for (int nf = 0; nf < 2; ++nf) {
                    int rloc = rh * 16 + l15;
                    int c    = w * 32 + nf * 16 + lk * 4;
                    *reinterpret_cast<float4*>(&lds_y[rloc * 132 + c]) =
                        make_float4(acc[rg][nf][0], acc[rg][nf][1],
                                    acc[rg][nf][2], acc[rg][nf][3]);
                }
            }
            __syncthreads();
            #pragma unroll
            for (int p = 0; p < 4; ++p) {
                int idx = tix + p * 256;
                int rr  = idx >> 5;
                int c4  = idx & 31;
                int row = bm + ch * 32 + rr;
                if (row < n && (uni || ntype[row] == t)) {
                    float4 val = *reinterpret_cast<const float4*>(
                        &lds_y[rr * 132 + c4 * 4]);
                    *reinterpret_cast<float4*>(&Y[(size_t)row * D + c4 * 4]) = val;
                }
            }
        }
    }
}

// ---------------------------------------------------------------------------
// Counting sort of edges by dst, then per-node gather-sum (no f32 atomics).
// ---------------------------------------------------------------------------
__global__ __launch_bounds__(256) void hist_kernel(
    const int* __restrict__ dst, int* __restrict__ counts, int ne)
{
    int stride = gridDim.x * blockDim.x;
    for (int e = blockIdx.x * blockDim.x + threadIdx.x; e < ne; e += stride)
        atomicAdd(&counts[dst[e]], 1);
}

__global__ __launch_bounds__(256) void scan1_kernel(
    const int* __restrict__ counts, int* __restrict__ offs,
    int* __restrict__ bsums, int n)
{
    __shared__ int lds[256];
    const int t    = threadIdx.x;
    const int base = blockIdx.x * SCAN_ELEMS + t * 4;

    int c[4]; int sum = 0;
    #pragma unroll
    for (int i = 0; i < 4; ++i) {
        c[i] = (base + i < n) ? counts[base + i] : 0;
        sum += c[i];
    }
    lds[t] = sum;
    __syncthreads();
    for (int off = 1; off < 256; off <<= 1) {
        int x = (t >= off) ? lds[t - off] : 0;
        __syncthreads();
        lds[t] += x;
        __syncthreads();
    }
    int run = (t == 0) ? 0 : lds[t - 1];
    #pragma unroll
    for (int i = 0; i < 4; ++i) {
        if (base + i < n) offs[base + i] = run;
        run += c[i];
    }
    if (t == 255) bsums[blockIdx.x] = lds[255];
}

__global__ __launch_bounds__(256) void scan2_kernel(int* __restrict__ bsums, int nb)
{
    __shared__ int lds[256];
    const int t    = threadIdx.x;
    const int base = t * 4;
    int c[4]; int sum = 0;
    #pragma unroll
    for (int i = 0; i < 4; ++i) {
        c[i] = (base + i < nb) ? bsums[base + i] : 0;
        sum += c[i];
    }
    lds[t] = sum;
    __syncthreads();
    for (int off = 1; off < 256; off <<= 1) {
        int x = (t >= off) ? lds[t - off] : 0;
        __syncthreads();
        lds[t] += x;
        __syncthreads();
    }
    int run = (t == 0) ? 0 : lds[t - 1];
    #pragma unroll
    for (int i = 0; i < 4; ++i) {
        if (base + i < nb) bsums[base + i] = run;
        run += c[i];
    }
}

__global__ __launch_bounds__(256) void scan3_kernel(
    int* __restrict__ offs, int* __restrict__ cursor,
    const int* __restrict__ bsums, int n)
{
    int i = blockIdx.x * blockDim.x + threadIdx.x;
    if (i < n) {
        int o = offs[i] + bsums[i / SCAN_ELEMS];
        offs[i]   = o;
        cursor[i] = o;
    }
}

__global__ __launch_bounds__(256) void place_kernel(
    const int* __restrict__ src, const int* __restrict__ dst,
    int* __restrict__ cursor, int* __restrict__ ssrc, int ne)
{
    int stride = gridDim.x * blockDim.x;
    for (int e = blockIdx.x * blockDim.x + threadIdx.x; e < ne; e += stride) {
        int d   = dst[e];
        int pos = atomicAdd(&cursor[d], 1);
        ssrc[pos] = src[e];
    }
}

// ---------------------------------------------------------------------------
// gather (bf16): one wave per node; 1 dword (2 bf16) per lane per edge row;
// f32 accumulate; bf16x2 store. Unrolled 4 edges for latency hiding.
// ---------------------------------------------------------------------------
__global__ __launch_bounds__(256) void gather_kernel(
    const __bf16* __restrict__ V, const int* __restrict__ offs,
    const int* __restrict__ counts, const int* __restrict__ ssrc,
    __bf16* __restrict__ H, int n)
{
    const int wid  = (int)((blockIdx.x * 256 + threadIdx.x) >> 6);
    const int lane = threadIdx.x & 63;
    if (wid >= n) return;

    const int beg = offs[wid];
    const int cnt = counts[wid];
    const unsigned int* V32 = reinterpret_cast<const unsigned int*>(V);

    float ax = 0.f, ay = 0.f;
    int j = 0;
    for (; j + 3 < cnt; j += 4) {
        int s0 = ssrc[beg + j];
        int s1 = ssrc[beg + j + 1];
        int s2 = ssrc[beg + j + 2];
        int s3 = ssrc[beg + j + 3];
        unsigned int u0 = V32[(size_t)s0 * 64 + lane];
        unsigned int u1 = V32[(size_t)s1 * 64 + lane];
        unsigned int u2 = V32[(size_t)s2 * 64 + lane];
        unsigned int u3 = V32[(size_t)s3 * 64 + lane];
        ax += __uint_as_float(u0 << 16) + __uint_as_float(u1 << 16)
            + __uint_as_float(u2 << 16) + __uint_as_float(u3 << 16);
        ay += __uint_as_float(u0 & 0xffff0000u) + __uint_as_float(u1 & 0xffff0000u)
            + __uint_as_float(u2 & 0xffff0000u) + __uint_as_float(u3 & 0xffff0000u);
    }
    for (; j < cnt; ++j) {
        int s = ssrc[beg + j];
        unsigned int u = V32[(size_t)s * 64 + lane];
        ax += __uint_as_float(u << 16);
        ay += __uint_as_float(u & 0xffff0000u);
    }

    bf16x2 o;
    o[0] = (__bf16)ax;
    o[1] = (__bf16)ay;
    reinterpret_cast<bf16x2*>(H)[(size_t)wid * 64 + lane] = o;
}

// ---------------------------------------------------------------------------
extern "C" void kernel_launch(void* const* d_in, const int* in_sizes, int n_in,
                              void* d_out, int out_size, void* d_ws, size_t ws_size,
                              hipStream_t stream)
{
    const float* x     = (const float*)d_in[0];
    const int*   ntype = (const int*)d_in[1];
    const int*   src   = (const int*)d_in[2];
    const int*   dst   = (const int*)d_in[3];
    const float* Wv    = (const float*)d_in[4];
    const float* Wa    = (const float*)d_in[5];

    const int n  = in_sizes[0] / D;   // 100000 nodes
    const int ne = in_sizes[2];       // 800000 edges

    // workspace layout (256B-aligned chunks)
    char* ws = (char*)d_ws;
    size_t off = 0;
    auto alloc = [&](size_t bytes) {
        void* p = ws + off;
        off += (bytes + 255) & ~(size_t)255;
        return p;
    };
    __bf16* v      = (__bf16*)alloc((size_t)n * D * sizeof(__bf16));
    __bf16* h      = (__bf16*)alloc((size_t)n * D * sizeof(__bf16));
    __bf16* wt     = (__bf16*)alloc((size_t)4 * 128 * 128 * sizeof(__bf16));
    int*    counts = (int*)   alloc((size_t)n * sizeof(int));
    int*    offs   = (int*)   alloc((size_t)n * sizeof(int));
    int*    cursor = (int*)   alloc((size_t)n * sizeof(int));
    int*    bsums  = (int*)   alloc(1024 * sizeof(int));
    int*    ssrc   = (int*)   alloc((size_t)ne * sizeof(int));

    float* out = (float*)d_out;

    hipMemsetAsync(counts, 0, (size_t)n * sizeof(int), stream);

    // prep: transposed bf16 weights (Wv -> wt[0..1], Wa -> wt[2..3])
    wprep_kernel<<<256, 256, 0, stream>>>(Wv, Wa, wt);

    // stage 1: v = bf16( typed_linear(x, W_v) )
    const int nblk = (n + 63) / 64;
    typed_mfma_f32_bf16<<<nblk, 256, 0, stream>>>(x, wt, ntype, v, n);

    // counting sort of edges by dst
    hist_kernel<<<1024, 256, 0, stream>>>(dst, counts, ne);
    const int nb = (n + SCAN_ELEMS - 1) / SCAN_ELEMS;
    scan1_kernel<<<nb, 256, 0, stream>>>(counts, offs, bsums, n);
    scan2_kernel<<<1, 256, 0, stream>>>(bsums, nb);
    scan3_kernel<<<(n + 255) / 256, 256, 0, stream>>>(offs, cursor, bsums, n);
    place_kernel<<<1024, 256, 0, stream>>>(src, dst, cursor, ssrc, ne);

    // stage 2: h = bf16( segment-sum over sorted edges )
    const int gblk = (n * 64 + 255) / 256;
    gather_kernel<<<gblk, 256, 0, stream>>>(v, offs, counts, ssrc, h, n);

    // stage 3: out = typed_linear(h, W_a)  [bf16 in, f32 out]
    typed_mfma_bf16_f32<<<nblk, 256, 0, stream>>>(h, wt + 2 * 128 * 128, ntype, out, n);
}

// Round 9
// 293.603 us; speedup vs baseline: 5.4070x; 1.0372x over previous
//
#include <hip/hip_runtime.h>

#define D 128
#define SCAN_ELEMS 1024   // elements per scan1 block (256 thr x 4)

typedef __attribute__((ext_vector_type(8))) __bf16 bf16x8;
typedef __attribute__((ext_vector_type(4))) __bf16 bf16x4;
typedef __attribute__((ext_vector_type(2))) __bf16 bf16x2;
typedef __attribute__((ext_vector_type(4))) float  f32x4;

// ---------------------------------------------------------------------------
// wprep: wt[m][col][k] = (bf16) W_m[k][col]   (m: 0,1 = Wv types; 2,3 = Wa)
// 4 x 128 x 128 bf16 = 128 KB, L2/L3-resident.
// ---------------------------------------------------------------------------
__global__ __launch_bounds__(256) void wprep_kernel(
    const float* __restrict__ Wv, const float* __restrict__ Wa,
    __bf16* __restrict__ wt)
{
    int idx = blockIdx.x * 256 + threadIdx.x;    // 0..65535
    int m   = idx >> 14;
    int col = (idx >> 7) & 127;
    int k   = idx & 127;
    const float* src = (m < 2) ? Wv + ((size_t)m * 128 + k) * 128 + col
                               : Wa + ((size_t)(m - 2) * 128 + k) * 128 + col;
    wt[idx] = (__bf16)(*src);
}

// ---------------------------------------------------------------------------
// Stage 1: V[r,:] = (bf16) X[r,:] @ W_v[ntype[r]]   (X f32 in, V bf16 out)
// Swapped-operand MFMA (D = Y^T frags: lane = 1 row x 4 cols) + LDS epilogue
// -> fully-coalesced bf16x8 stores (256 B per row, no RMW).
// ---------------------------------------------------------------------------
__global__ __launch_bounds__(256, 4) void typed_mfma_f32_bf16(
    const float* __restrict__ X, const __bf16* __restrict__ WT,
    const int* __restrict__ ntype, __bf16* __restrict__ V, int n)
{
    __shared__ __bf16 lds_v[32 * 136];   // 32-row chunk, +8 bf16 pad per row

    const int tix = threadIdx.x;
    const int w   = tix >> 6;
    const int l   = tix & 63;
    const int l15 = l & 15;
    const int lk  = l >> 4;
    const int bm  = blockIdx.x * 64;

    const int last = (bm + 63 < n) ? bm + 63 : n - 1;
    const int t0   = ntype[bm];
    const int t1   = ntype[last];
    const bool uni = (t0 == t1);

    for (int t = t0; t <= t1; ++t) {
        const __bf16* wb = WT + ((size_t)t << 14);
        bf16x8 wfr[4][2];
        #pragma unroll
        for (int ks = 0; ks < 4; ++ks)
            #pragma unroll
            for (int nf = 0; nf < 2; ++nf) {
                int col = w * 32 + nf * 16 + l15;
                wfr[ks][nf] = *reinterpret_cast<const bf16x8*>(
                    wb + col * 128 + ks * 32 + lk * 8);
            }

        f32x4 acc[4][2];
        #pragma unroll
        for (int rg = 0; rg < 4; ++rg)
            #pragma unroll
            for (int nf = 0; nf < 2; ++nf)
                acc[rg][nf] = (f32x4){0.f, 0.f, 0.f, 0.f};

        #pragma unroll
        for (int rg = 0; rg < 4; ++rg) {
            int row = bm + rg * 16 + l15;
            if (row > n - 1) row = n - 1;
            const float* xr = X + (size_t)row * D + lk * 8;
            #pragma unroll
            for (int ks = 0; ks < 4; ++ks) {
                float4 f0 = *reinterpret_cast<const float4*>(xr + ks * 32);
                float4 f1 = *reinterpret_cast<const float4*>(xr + ks * 32 + 4);
                bf16x8 a;
                a[0] = (__bf16)f0.x; a[1] = (__bf16)f0.y;
                a[2] = (__bf16)f0.z; a[3] = (__bf16)f0.w;
                a[4] = (__bf16)f1.x; a[5] = (__bf16)f1.y;
                a[6] = (__bf16)f1.z; a[7] = (__bf16)f1.w;
                acc[rg][0] = __builtin_amdgcn_mfma_f32_16x16x32_bf16(
                    wfr[ks][0], a, acc[rg][0], 0, 0, 0);
                acc[rg][1] = __builtin_amdgcn_mfma_f32_16x16x32_bf16(
                    wfr[ks][1], a, acc[rg][1], 0, 0, 0);
            }
        }

        #pragma unroll
        for (int ch = 0; ch < 2; ++ch) {
            __syncthreads();
            #pragma unroll
            for (int rh = 0; rh < 2; ++rh) {
                int rg = ch * 2 + rh;
                #pragma unroll
                for (int nf = 0; nf < 2; ++nf) {
                    int rloc = rh * 16 + l15;
                    int c    = w * 32 + nf * 16 + lk * 4;
                    bf16x4 o;
                    o[0] = (__bf16)acc[rg][nf][0];
                    o[1] = (__bf16)acc[rg][nf][1];
                    o[2] = (__bf16)acc[rg][nf][2];
                    o[3] = (__bf16)acc[rg][nf][3];
                    *reinterpret_cast<bf16x4*>(&lds_v[rloc * 136 + c]) = o;
                }
            }
            __syncthreads();
            #pragma unroll
            for (int p = 0; p < 2; ++p) {
                int idx = tix + p * 256;          // 0..511 = 32 rows x 16 col8
                int rr  = idx >> 4;
                int c8  = idx & 15;
                int row = bm + ch * 32 + rr;
                if (row < n && (uni || ntype[row] == t)) {
                    bf16x8 val = *reinterpret_cast<const bf16x8*>(
                        &lds_v[rr * 136 + c8 * 8]);
                    *reinterpret_cast<bf16x8*>(&V[(size_t)row * D + c8 * 8]) = val;
                }
            }
        }
    }
}

// ---------------------------------------------------------------------------
// Stage 3: Y[r,:] = H[r,:] @ W_a[ntype[r]]   (H bf16 in, Y f32 out)
// ---------------------------------------------------------------------------
__global__ __launch_bounds__(256, 4) void typed_mfma_bf16_f32(
    const __bf16* __restrict__ H, const __bf16* __restrict__ WT,
    const int* __restrict__ ntype, float* __restrict__ Y, int n)
{
    __shared__ float lds_y[32 * 132];

    const int tix = threadIdx.x;
    const int w   = tix >> 6;
    const int l   = tix & 63;
    const int l15 = l & 15;
    const int lk  = l >> 4;
    const int bm  = blockIdx.x * 64;

    const int last = (bm + 63 < n) ? bm + 63 : n - 1;
    const int t0   = ntype[bm];
    const int t1   = ntype[last];
    const bool uni = (t0 == t1);

    for (int t = t0; t <= t1; ++t) {
        const __bf16* wb = WT + ((size_t)t << 14);
        bf16x8 wfr[4][2];
        #pragma unroll
        for (int ks = 0; ks < 4; ++ks)
            #pragma unroll
            for (int nf = 0; nf < 2; ++nf) {
                int col = w * 32 + nf * 16 + l15;
                wfr[ks][nf] = *reinterpret_cast<const bf16x8*>(
                    wb + col * 128 + ks * 32 + lk * 8);
            }

        f32x4 acc[4][2];
        #pragma unroll
        for (int rg = 0; rg < 4; ++rg)
            #pragma unroll
            for (int nf = 0; nf < 2; ++nf)
                acc[rg][nf] = (f32x4){0.f, 0.f, 0.f, 0.f};

        #pragma unroll
        for (int rg = 0; rg < 4; ++rg) {
            int row = bm + rg * 16 + l15;
            if (row > n - 1) row = n - 1;
            const __bf16* hr = H + (size_t)row * D + lk * 8;
            #pragma unroll
            for (int ks = 0; ks < 4; ++ks) {
                bf16x8 a = *reinterpret_cast<const bf16x8*>(hr + ks * 32);
                acc[rg][0] = __builtin_amdgcn_mfma_f32_16x16x32_bf16(
                    wfr[ks][0], a, acc[rg][0], 0, 0, 0);
                acc[rg][1] = __builtin_amdgcn_mfma_f32_16x16x32_bf16(
                    wfr[ks][1], a, acc[rg][1], 0, 0, 0);
            }
        }

        #pragma unroll
        for (int ch = 0; ch < 2; ++ch) {
            __syncthreads();
            #pragma unroll
            for (int rh = 0; rh < 2; ++rh) {
                int rg = ch * 2 + rh;
                #pragma unroll
                for (int nf = 0; nf < 2; ++nf) {
                    int rloc = rh * 16 + l15;
                    int c    = w * 32 + nf * 16 + lk * 4;
                    *reinterpret_cast<float4*>(&lds_y[rloc * 132 + c]) =
                        make_float4(acc[rg][nf][0], acc[rg][nf][1],
                                    acc[rg][nf][2], acc[rg][nf][3]);
                }
            }
            __syncthreads();
            #pragma unroll
            for (int p = 0; p < 4; ++p) {
                int idx = tix + p * 256;
                int rr  = idx >> 5;
                int c4  = idx & 31;
                int row = bm + ch * 32 + rr;
                if (row < n && (uni || ntype[row] == t)) {
                    float4 val = *reinterpret_cast<const float4*>(
                        &lds_y[rr * 132 + c4 * 4]);
                    *reinterpret_cast<float4*>(&Y[(size_t)row * D + c4 * 4]) = val;
                }
            }
        }
    }
}

// ---------------------------------------------------------------------------
// Counting sort of edges by dst, then per-node gather-sum (no f32 atomics).
// ---------------------------------------------------------------------------
__global__ __launch_bounds__(256) void hist_kernel(
    const int* __restrict__ dst, int* __restrict__ counts, int ne)
{
    int stride = gridDim.x * blockDim.x;
    for (int e = blockIdx.x * blockDim.x + threadIdx.x; e < ne; e += stride)
        atomicAdd(&counts[dst[e]], 1);
}

__global__ __launch_bounds__(256) void scan1_kernel(
    const int* __restrict__ counts, int* __restrict__ offs,
    int* __restrict__ bsums, int n)
{
    __shared__ int lds[256];
    const int t    = threadIdx.x;
    const int base = blockIdx.x * SCAN_ELEMS + t * 4;

    int c[4]; int sum = 0;
    #pragma unroll
    for (int i = 0; i < 4; ++i) {
        c[i] = (base + i < n) ? counts[base + i] : 0;
        sum += c[i];
    }
    lds[t] = sum;
    __syncthreads();
    for (int off = 1; off < 256; off <<= 1) {
        int x = (t >= off) ? lds[t - off] : 0;
        __syncthreads();
        lds[t] += x;
        __syncthreads();
    }
    int run = (t == 0) ? 0 : lds[t - 1];
    #pragma unroll
    for (int i = 0; i < 4; ++i) {
        if (base + i < n) offs[base + i] = run;
        run += c[i];
    }
    if (t == 255) bsums[blockIdx.x] = lds[255];
}

__global__ __launch_bounds__(256) void scan2_kernel(int* __restrict__ bsums, int nb)
{
    __shared__ int lds[256];
    const int t    = threadIdx.x;
    const int base = t * 4;
    int c[4]; int sum = 0;
    #pragma unroll
    for (int i = 0; i < 4; ++i) {
        c[i] = (base + i < nb) ? bsums[base + i] : 0;
        sum += c[i];
    }
    lds[t] = sum;
    __syncthreads();
    for (int off = 1; off < 256; off <<= 1) {
        int x = (t >= off) ? lds[t - off] : 0;
        __syncthreads();
        lds[t] += x;
        __syncthreads();
    }
    int run = (t == 0) ? 0 : lds[t - 1];
    #pragma unroll
    for (int i = 0; i < 4; ++i) {
        if (base + i < nb) bsums[base + i] = run;
        run += c[i];
    }
}

__global__ __launch_bounds__(256) void scan3_kernel(
    int* __restrict__ offs, int* __restrict__ cursor,
    const int* __restrict__ bsums, int n)
{
    int i = blockIdx.x * blockDim.x + threadIdx.x;
    if (i < n) {
        int o = offs[i] + bsums[i / SCAN_ELEMS];
        offs[i]   = o;
        cursor[i] = o;
    }
}

// ---------------------------------------------------------------------------
// place, XCD-partitioned: blocks with (bid&7)==g own dst range
// [g*rpx, (g+1)*rpx) and write only those edges -> each 64B ssrc line is
// dirtied by ONE XCD's L2 (empirical bid%8->XCD mapping), killing the 17x
// write-back amplification seen in round 8 (WRITE_SIZE 54MB for 3.2MB data).
// All 8 groups stream the full src/dst arrays (L3-resident, cheap).
// Correctness does not depend on the mapping; only locality does.
// ---------------------------------------------------------------------------
__global__ __launch_bounds__(256) void place_kernel(
    const int* __restrict__ src, const int* __restrict__ dst,
    int* __restrict__ cursor, int* __restrict__ ssrc, int ne, int rpx)
{
    const int g     = blockIdx.x & 7;          // XCD group
    const int chunk = blockIdx.x >> 3;         // 0..(gridDim/8-1)
    const int lo    = g * rpx;
    const int hi    = lo + rpx;
    const int stride = (gridDim.x >> 3) * blockDim.x;

    for (int e = chunk * blockDim.x + threadIdx.x; e < ne; e += stride) {
        int d = dst[e];
        if (d >= lo && d < hi) {
            int pos = atomicAdd(&cursor[d], 1);
            ssrc[pos] = src[e];
        }
    }
}

// ---------------------------------------------------------------------------
// gather (bf16): one wave per node; 1 dword (2 bf16) per lane per edge row;
// f32 accumulate; bf16x2 store. Unrolled 4 edges for latency hiding.
// ---------------------------------------------------------------------------
__global__ __launch_bounds__(256) void gather_kernel(
    const __bf16* __restrict__ V, const int* __restrict__ offs,
    const int* __restrict__ counts, const int* __restrict__ ssrc,
    __bf16* __restrict__ H, int n)
{
    const int wid  = (int)((blockIdx.x * 256 + threadIdx.x) >> 6);
    const int lane = threadIdx.x & 63;
    if (wid >= n) return;

    const int beg = offs[wid];
    const int cnt = counts[wid];
    const unsigned int* V32 = reinterpret_cast<const unsigned int*>(V);

    float ax = 0.f, ay = 0.f;
    int j = 0;
    for (; j + 3 < cnt; j += 4) {
        int s0 = ssrc[beg + j];
        int s1 = ssrc[beg + j + 1];
        int s2 = ssrc[beg + j + 2];
        int s3 = ssrc[beg + j + 3];
        unsigned int u0 = V32[(size_t)s0 * 64 + lane];
        unsigned int u1 = V32[(size_t)s1 * 64 + lane];
        unsigned int u2 = V32[(size_t)s2 * 64 + lane];
        unsigned int u3 = V32[(size_t)s3 * 64 + lane];
        ax += __uint_as_float(u0 << 16) + __uint_as_float(u1 << 16)
            + __uint_as_float(u2 << 16) + __uint_as_float(u3 << 16);
        ay += __uint_as_float(u0 & 0xffff0000u) + __uint_as_float(u1 & 0xffff0000u)
            + __uint_as_float(u2 & 0xffff0000u) + __uint_as_float(u3 & 0xffff0000u);
    }
    for (; j < cnt; ++j) {
        int s = ssrc[beg + j];
        unsigned int u = V32[(size_t)s * 64 + lane];
        ax += __uint_as_float(u << 16);
        ay += __uint_as_float(u & 0xffff0000u);
    }

    bf16x2 o;
    o[0] = (__bf16)ax;
    o[1] = (__bf16)ay;
    reinterpret_cast<bf16x2*>(H)[(size_t)wid * 64 + lane] = o;
}

// ---------------------------------------------------------------------------
extern "C" void kernel_launch(void* const* d_in, const int* in_sizes, int n_in,
                              void* d_out, int out_size, void* d_ws, size_t ws_size,
                              hipStream_t stream)
{
    const float* x     = (const float*)d_in[0];
    const int*   ntype = (const int*)d_in[1];
    const int*   src   = (const int*)d_in[2];
    const int*   dst   = (const int*)d_in[3];
    const float* Wv    = (const float*)d_in[4];
    const float* Wa    = (const float*)d_in[5];

    const int n  = in_sizes[0] / D;   // 100000 nodes
    const int ne = in_sizes[2];       // 800000 edges

    // workspace layout (256B-aligned chunks)
    char* ws = (char*)d_ws;
    size_t off = 0;
    auto alloc = [&](size_t bytes) {
        void* p = ws + off;
        off += (bytes + 255) & ~(size_t)255;
        return p;
    };
    __bf16* v      = (__bf16*)alloc((size_t)n * D * sizeof(__bf16));
    __bf16* h      = (__bf16*)alloc((size_t)n * D * sizeof(__bf16));
    __bf16* wt     = (__bf16*)alloc((size_t)4 * 128 * 128 * sizeof(__bf16));
    int*    counts = (int*)   alloc((size_t)n * sizeof(int));
    int*    offs   = (int*)   alloc((size_t)n * sizeof(int));
    int*    cursor = (int*)   alloc((size_t)n * sizeof(int));
    int*    bsums  = (int*)   alloc(1024 * sizeof(int));
    int*    ssrc   = (int*)   alloc((size_t)ne * sizeof(int));

    float* out = (float*)d_out;

    hipMemsetAsync(counts, 0, (size_t)n * sizeof(int), stream);

    // prep: transposed bf16 weights (Wv -> wt[0..1], Wa -> wt[2..3])
    wprep_kernel<<<256, 256, 0, stream>>>(Wv, Wa, wt);

    // stage 1: v = bf16( typed_linear(x, W_v) )
    const int nblk = (n + 63) / 64;
    typed_mfma_f32_bf16<<<nblk, 256, 0, stream>>>(x, wt, ntype, v, n);

    // counting sort of edges by dst
    hist_kernel<<<1024, 256, 0, stream>>>(dst, counts, ne);
    const int nb = (n + SCAN_ELEMS - 1) / SCAN_ELEMS;
    scan1_kernel<<<nb, 256, 0, stream>>>(counts, offs, bsums, n);
    scan2_kernel<<<1, 256, 0, stream>>>(bsums, nb);
    scan3_kernel<<<(n + 255) / 256, 256, 0, stream>>>(offs, cursor, bsums, n);
    const int rpx = (n + 7) / 8;
    place_kernel<<<1024, 256, 0, stream>>>(src, dst, cursor, ssrc, ne, rpx);

    // stage 2: h = bf16( segment-sum over sorted edges )
    const int gblk = (n * 64 + 255) / 256;
    gather_kernel<<<gblk, 256, 0, stream>>>(v, offs, counts, ssrc, h, n);

    // stage 3: out = typed_linear(h, W_a)  [bf16 in, f32 out]
    typed_mfma_bf16_f32<<<nblk, 256, 0, stream>>>(h, wt + 2 * 128 * 128, ntype, out, n);
}